// Round 21
// baseline (291.935 us; speedup 1.0000x reference)
//
#include <hip/hip_runtime.h>

#define NPOS 512
#define NN_ (512 * 512)

typedef unsigned short u16;
typedef __attribute__((ext_vector_type(8))) short bf16x8_t;  // 8 bf16 in 4 VGPRs
typedef __attribute__((ext_vector_type(4))) float f32x4_t;   // MFMA acc

__device__ __forceinline__ float bf2f(u16 u) {
  union { unsigned int i; float f; } v;
  v.i = ((unsigned int)u) << 16;
  return v.f;
}
// Native HW bf16 convert (RNE).
__device__ __forceinline__ u16 f2bf(float f) {
  __bf16 h = (__bf16)f;
  return __builtin_bit_cast(unsigned short, h);
}
__device__ __forceinline__ float sigm(float x) { return 1.0f / (1.0f + __expf(-x)); }

// async global->LDS, 16B per lane (dest must be wave-linear: base + lane*16).
__device__ __forceinline__ void gld_lds16(u16* lds, const u16* g) {
  __builtin_amdgcn_global_load_lds(
      (const __attribute__((address_space(1))) unsigned int*)g,
      (__attribute__((address_space(3))) unsigned int*)lds, 16, 0, 0);
}

// ---------------------------------------------------------------------------
// K0: pre-transpose 5 projection weights to bf16 Wt[o][k] (k contiguous).
// ---------------------------------------------------------------------------
__global__ __launch_bounds__(256) void k0_wt(const float* __restrict__ wl,
                                             const float* __restrict__ wgl,
                                             const float* __restrict__ wr,
                                             const float* __restrict__ wgr,
                                             const float* __restrict__ wgate,
                                             u16* __restrict__ wtbase) {
  int b = blockIdx.x;
  int wi = b >> 3;
  int o0 = (b & 7) * 16;
  const float* W = wi == 0 ? wl : wi == 1 ? wgl : wi == 2 ? wr : wi == 3 ? wgr : wgate;
  u16* dst = wtbase + wi * 16384;
  int t = threadIdx.x;
  int o = o0 + (t >> 4);
  int k0 = (t & 15) * 8;
  float v[8];
#pragma unroll
  for (int i = 0; i < 8; ++i) v[i] = W[(k0 + i) * 128 + o];
  ushort4 a, b4;
  a.x = f2bf(v[0]); a.y = f2bf(v[1]); a.z = f2bf(v[2]); a.w = f2bf(v[3]);
  b4.x = f2bf(v[4]); b4.y = f2bf(v[5]); b4.z = f2bf(v[6]); b4.w = f2bf(v[7]);
  *(ushort4*)(dst + o * 128 + k0) = a;
  *(ushort4*)(dst + o * 128 + k0 + 4) = b4;
}

// ---------------------------------------------------------------------------
// K0b: transpose wout -> bf16 Wt6[o][k], into dead Lt region (after k3).
// ---------------------------------------------------------------------------
__global__ __launch_bounds__(256) void k0b(const float* __restrict__ wout,
                                           u16* __restrict__ Wt6) {
  int o = blockIdx.x * 16 + (threadIdx.x >> 4);
  int k0 = (threadIdx.x & 15) * 8;
  float v[8];
#pragma unroll
  for (int i = 0; i < 8; ++i) v[i] = wout[(k0 + i) * 128 + o];
  ushort4 a, b4;
  a.x = f2bf(v[0]); a.y = f2bf(v[1]); a.z = f2bf(v[2]); a.w = f2bf(v[3]);
  b4.x = f2bf(v[4]); b4.y = f2bf(v[5]); b4.z = f2bf(v[6]); b4.w = f2bf(v[7]);
  *(ushort4*)(Wt6 + o * 128 + k0) = a;
  *(ushort4*)(Wt6 + o * 128 + k0 + 4) = b4;
}

// ---------------------------------------------------------------------------
// K2_fused v12: = v10 + mask float4s hoisted to registers (were re-loaded in
// every EPW) and per-EPW slot/off math hoisted. Input LN + 4 projection
// GEMMs, TWO 128-pos tiles/block sharing staged weights; tile0 A-frags in
// regs, tile1 A from xn LDS. Gx export fused into LN. LDS 80KB, grid 1024.
// ---------------------------------------------------------------------------
__global__ __launch_bounds__(512, 4) void k2_fused(
    const float* __restrict__ act, const float* __restrict__ mask,
    const u16* __restrict__ wtbase,
    const float* __restrict__ ln_g, const float* __restrict__ ln_b,
    const float* __restrict__ bl, const float* __restrict__ bgl,
    const float* __restrict__ br, const float* __restrict__ bgr,
    u16* __restrict__ Lt, u16* __restrict__ Rt, u16* __restrict__ Gx) {
  __shared__ __align__(16) unsigned char smem[81920];
  u16* xn  = (u16*)smem;                     // [128 p][128 c] swizzled (tile1 resident)
  u16* wh0 = (u16*)(smem + 32768);           // [64 o][128 k] proj half
  u16* wh1 = (u16*)(smem + 49152);           // [64 o][128 k] gate half
  u16* ob  = (u16*)(smem + 65536);           // [64 o][128 p] epilogue buffer

  int tid = threadIdx.x;
  int l = tid & 63, w = tid >> 6;
  int wr_ = w >> 1, wc = w & 1;              // 32-pos band x 32-out band
  int lr = l & 15, lk = l >> 4;
  size_t p0 = (size_t)blockIdx.x * 256;      // tile0 base
  size_t p1 = p0 + 128;                      // tile1 base

  // epilogue row geometry (per-thread constants)
  int ep0 = wr_ * 32 + lk * 4;               // m=0 position offset
  int ep1 = ep0 + 16;                        // m=1 position offset
  int slot0 = (ep0 >> 3), off0 = ep0 & 7;
  int slot1 = (ep1 >> 3), off1 = ep1 & 7;

#define STAGE(i_, buf_)                                                     \
  {                                                                         \
    const u16* src = wtbase + ((i_) >> 1) * 16384 + ((i_) & 1) * 8192;      \
    _Pragma("unroll") for (int q = 0; q < 2; ++q) {                         \
      int s = q * 512 + tid;                                                \
      int row = s >> 4, j = (s & 15) ^ (row & 7);                           \
      gld_lds16((buf_) + s * 8, src + row * 128 + j * 8);                   \
    }                                                                       \
  }
#define ZERO(ACC)                                                           \
  { ACC[0][0] = (f32x4_t){0.f, 0.f, 0.f, 0.f};                              \
    ACC[0][1] = (f32x4_t){0.f, 0.f, 0.f, 0.f};                              \
    ACC[1][0] = (f32x4_t){0.f, 0.f, 0.f, 0.f};                              \
    ACC[1][1] = (f32x4_t){0.f, 0.f, 0.f, 0.f}; }
// tile0 MF step: A from named registers
#define MFK0(buf_, ACC, KT, AF0, AF1)                                       \
  {                                                                         \
    int kb = (KT) * 4 + lk;                                                 \
    int o0_ = wc * 32 + lr, o1_ = wc * 32 + 16 + lr;                        \
    bf16x8_t bfr0 = *(const bf16x8_t*)((buf_) + o0_ * 128 + ((kb ^ (o0_ & 7)) * 8)); \
    bf16x8_t bfr1 = *(const bf16x8_t*)((buf_) + o1_ * 128 + ((kb ^ (o1_ & 7)) * 8)); \
    ACC[0][0] = __builtin_amdgcn_mfma_f32_16x16x32_bf16(AF0, bfr0, ACC[0][0], 0, 0, 0); \
    ACC[0][1] = __builtin_amdgcn_mfma_f32_16x16x32_bf16(AF0, bfr1, ACC[0][1], 0, 0, 0); \
    ACC[1][0] = __builtin_amdgcn_mfma_f32_16x16x32_bf16(AF1, bfr0, ACC[1][0], 0, 0, 0); \
    ACC[1][1] = __builtin_amdgcn_mfma_f32_16x16x32_bf16(AF1, bfr1, ACC[1][1], 0, 0, 0); \
  }
#define MF0(buf_, ACC)                                                      \
  MFK0(buf_, ACC, 0, af00, af10)                                            \
  MFK0(buf_, ACC, 1, af01, af11)                                            \
  MFK0(buf_, ACC, 2, af02, af12)                                            \
  MFK0(buf_, ACC, 3, af03, af13)
// tile1 MF step: A from xn LDS
#define MFK1(buf_, ACC, KT)                                                 \
  {                                                                         \
    int kb = (KT) * 4 + lk;                                                 \
    int r0_ = wr_ * 32 + lr, r1_ = wr_ * 32 + 16 + lr;                      \
    bf16x8_t a0_ = *(const bf16x8_t*)(xn + r0_ * 128 + ((kb ^ (r0_ & 7)) * 8)); \
    bf16x8_t a1_ = *(const bf16x8_t*)(xn + r1_ * 128 + ((kb ^ (r1_ & 7)) * 8)); \
    int o0_ = wc * 32 + lr, o1_ = wc * 32 + 16 + lr;                        \
    bf16x8_t bfr0 = *(const bf16x8_t*)((buf_) + o0_ * 128 + ((kb ^ (o0_ & 7)) * 8)); \
    bf16x8_t bfr1 = *(const bf16x8_t*)((buf_) + o1_ * 128 + ((kb ^ (o1_ & 7)) * 8)); \
    ACC[0][0] = __builtin_amdgcn_mfma_f32_16x16x32_bf16(a0_, bfr0, ACC[0][0], 0, 0, 0); \
    ACC[0][1] = __builtin_amdgcn_mfma_f32_16x16x32_bf16(a0_, bfr1, ACC[0][1], 0, 0, 0); \
    ACC[1][0] = __builtin_amdgcn_mfma_f32_16x16x32_bf16(a1_, bfr0, ACC[1][0], 0, 0, 0); \
    ACC[1][1] = __builtin_amdgcn_mfma_f32_16x16x32_bf16(a1_, bfr1, ACC[1][1], 0, 0, 0); \
  }
#define MF1(buf_, ACC)                                                      \
  MFK1(buf_, ACC, 0) MFK1(buf_, ACC, 1) MFK1(buf_, ACC, 2) MFK1(buf_, ACC, 3)
// epilogue write: mask (register float4s) * (p+b) * sigm(g+b) into ob
#define EPW(ACCP, ACCG, Bp_, Bg_, obase_, MK0_, MK1_)                       \
  {                                                                         \
    float bpv[2], bgv[2];                                                   \
    _Pragma("unroll") for (int n = 0; n < 2; ++n) {                         \
      int og = (obase_) + wc * 32 + n * 16 + lr;                            \
      bpv[n] = Bp_[og]; bgv[n] = Bg_[og];                                   \
    }                                                                       \
    _Pragma("unroll") for (int n = 0; n < 2; ++n) {                         \
      int ol = wc * 32 + n * 16 + lr;                                       \
      ushort4 v0, v1;                                                       \
      v0.x = f2bf(MK0_.x * (ACCP[0][n][0] + bpv[n]) * sigm(ACCG[0][n][0] + bgv[n])); \
      v0.y = f2bf(MK0_.y * (ACCP[0][n][1] + bpv[n]) * sigm(ACCG[0][n][1] + bgv[n])); \
      v0.z = f2bf(MK0_.z * (ACCP[0][n][2] + bpv[n]) * sigm(ACCG[0][n][2] + bgv[n])); \
      v0.w = f2bf(MK0_.w * (ACCP[0][n][3] + bpv[n]) * sigm(ACCG[0][n][3] + bgv[n])); \
      v1.x = f2bf(MK1_.x * (ACCP[1][n][0] + bpv[n]) * sigm(ACCG[1][n][0] + bgv[n])); \
      v1.y = f2bf(MK1_.y * (ACCP[1][n][1] + bpv[n]) * sigm(ACCG[1][n][1] + bgv[n])); \
      v1.z = f2bf(MK1_.z * (ACCP[1][n][2] + bpv[n]) * sigm(ACCG[1][n][2] + bgv[n])); \
      v1.w = f2bf(MK1_.w * (ACCP[1][n][3] + bpv[n]) * sigm(ACCG[1][n][3] + bgv[n])); \
      *(ushort4*)(ob + ol * 128 + ((slot0 ^ (ol & 7)) << 3) + off0) = v0;   \
      *(ushort4*)(ob + ol * 128 + ((slot1 ^ (ol & 7)) << 3) + off1) = v1;   \
    }                                                                       \
  }
#define EPS(Tdst_, obase_, TB_)                                             \
  {                                                                         \
    _Pragma("unroll") for (int it = 0; it < 2; ++it) {                      \
      int s = it * 512 + tid;                                               \
      int ol = s >> 4, c8 = s & 15;                                         \
      *(uint4*)(Tdst_ + (size_t)((obase_) + ol) * NN_ + (TB_) + c8 * 8) =   \
          *(const uint4*)(ob + ol * 128 + ((c8 ^ (ol & 7)) << 3));          \
    }                                                                       \
  }
// LN for one tile into xn; Gx export fused (coalesced 256B per 32-lane group)
#define LN_TILE(TB_)                                                        \
  _Pragma("unroll")                                                         \
  for (int r = 0; r < 8; ++r) {                                             \
    int f = r * 512 + tid;                                                  \
    int pos = f >> 5, c4 = f & 31;                                          \
    float4 v = *(const float4*)(act + ((TB_) + pos) * 128 + c4 * 4);        \
    float s1 = v.x + v.y + v.z + v.w;                                       \
    float s2 = v.x * v.x + v.y * v.y + v.z * v.z + v.w * v.w;               \
    _Pragma("unroll") for (int m = 1; m < 32; m <<= 1) {                    \
      s1 += __shfl_xor(s1, m);                                              \
      s2 += __shfl_xor(s2, m);                                              \
    }                                                                       \
    float mu = s1 * (1.0f / 128.0f);                                        \
    float rstd = rsqrtf(s2 * (1.0f / 128.0f) - mu * mu + 1e-5f);            \
    int cb = c4 * 4;                                                        \
    float4 gg = *(const float4*)(ln_g + cb);                                \
    float4 bb = *(const float4*)(ln_b + cb);                                \
    ushort4 o4;                                                             \
    o4.x = f2bf((v.x - mu) * rstd * gg.x + bb.x);                           \
    o4.y = f2bf((v.y - mu) * rstd * gg.y + bb.y);                           \
    o4.z = f2bf((v.z - mu) * rstd * gg.z + bb.z);                           \
    o4.w = f2bf((v.w - mu) * rstd * gg.w + bb.w);                           \
    int c8 = c4 >> 1, off = (c4 & 1) * 4;                                   \
    int so = pos * 128 + ((c8 ^ (pos & 7)) << 3) + off;                     \
    *(ushort4*)(xn + so) = o4;                                              \
    *(ushort4*)(Gx + (size_t)(TB_) * 128 + so) = o4;                        \
  }
// one weight half-pair section over both tiles
#define SECTION(Bp_, Bg_, obase_, Tdst_, DO_STAGE_, s0_, s1_)               \
  __builtin_amdgcn_s_setprio(1);                                            \
  ZERO(ap); MF0(wh0, ap);                                                   \
  ZERO(ag); MF0(wh1, ag);                                                   \
  __builtin_amdgcn_s_setprio(0);                                            \
  __syncthreads();                                                          \
  EPW(ap, ag, Bp_, Bg_, obase_, mkA0, mkA1);                                \
  __syncthreads();                                                          \
  EPS(Tdst_, obase_, p0);                                                   \
  __builtin_amdgcn_s_setprio(1);                                            \
  ZERO(ap); MF1(wh0, ap);                                                   \
  ZERO(ag); MF1(wh1, ag);                                                   \
  __builtin_amdgcn_s_setprio(0);                                            \
  __syncthreads();                                                          \
  if (DO_STAGE_) { STAGE(s0_, wh0); STAGE(s1_, wh1); }                      \
  EPW(ap, ag, Bp_, Bg_, obase_, mkB0, mkB1);                                \
  __syncthreads();                                                          \
  EPS(Tdst_, obase_, p1);

  // ---- prologue: issue wl.h0 + wgl.h0; LN both tiles; hoist tile0 ----
  STAGE(0, wh0);   // wl.h0
  STAGE(2, wh1);   // wgl.h0

  // hoist mask float4s (re-used by every EPW)
  float4 mkA0 = *(const float4*)(mask + p0 + ep0);
  float4 mkA1 = *(const float4*)(mask + p0 + ep1);
  float4 mkB0 = *(const float4*)(mask + p1 + ep0);
  float4 mkB1 = *(const float4*)(mask + p1 + ep1);

  LN_TILE(p0);
  __syncthreads();                    // xn(tile0) visible

  bf16x8_t af00, af01, af02, af03, af10, af11, af12, af13;
  {
    int row0 = wr_ * 32 + lr;
    int row1 = wr_ * 32 + 16 + lr;
    const u16* x0 = xn + row0 * 128;
    const u16* x1 = xn + row1 * 128;
    af00 = *(const bf16x8_t*)(x0 + (((0 * 4 + lk) ^ (row0 & 7)) * 8));
    af01 = *(const bf16x8_t*)(x0 + (((1 * 4 + lk) ^ (row0 & 7)) * 8));
    af02 = *(const bf16x8_t*)(x0 + (((2 * 4 + lk) ^ (row0 & 7)) * 8));
    af03 = *(const bf16x8_t*)(x0 + (((3 * 4 + lk) ^ (row0 & 7)) * 8));
    af10 = *(const bf16x8_t*)(x1 + (((0 * 4 + lk) ^ (row1 & 7)) * 8));
    af11 = *(const bf16x8_t*)(x1 + (((1 * 4 + lk) ^ (row1 & 7)) * 8));
    af12 = *(const bf16x8_t*)(x1 + (((2 * 4 + lk) ^ (row1 & 7)) * 8));
    af13 = *(const bf16x8_t*)(x1 + (((3 * 4 + lk) ^ (row1 & 7)) * 8));
  }
  __syncthreads();                    // all hoist reads done -> xn reusable

  LN_TILE(p1);                        // tile1 LN into xn (stays resident)
  __syncthreads();                    // xn(tile1) visible; S0/S2 drained

  f32x4_t ap[2][2], ag[2][2];         // only TWO acc sets live at any time

  SECTION(bl, bgl, 0,  Lt, 1, 1, 3);  // L.h0 ; stage wl.h1, wgl.h1
  SECTION(bl, bgl, 64, Lt, 1, 4, 6);  // L.h1 ; stage wr.h0, wgr.h0
  SECTION(br, bgr, 0,  Rt, 1, 5, 7);  // R.h0 ; stage wr.h1, wgr.h1
  SECTION(br, bgr, 64, Rt, 0, 0, 0);  // R.h1 ; no further stages
#undef STAGE
#undef ZERO
#undef MFK0
#undef MF0
#undef MFK1
#undef MF1
#undef EPW
#undef EPS
#undef LN_TILE
#undef SECTION
}

// ---------------------------------------------------------------------------
// K3 (MFMA) v2: per-channel NT GEMM, 128x256 tile, 512 thr = 8 waves (2x4),
// each wave 64x64. LDS 48KB; XCD-chunked swizzle; setprio (T5).
// ---------------------------------------------------------------------------
__global__ __launch_bounds__(512, 4) void k3_einsum_mfma(const u16* __restrict__ Lt,
                                                         const u16* __restrict__ Rt,
                                                         u16* __restrict__ Ot) {
  __shared__ __align__(16) u16 smem[3 * 128 * 64];  // 48KB
  u16* La = smem;                 // [128][64]
  u16* Rb = smem + 128 * 64;      // [256][64]
  u16* ob = smem;                 // epilogue [128][128] overlay

  int tid = threadIdx.x;
  int bid = blockIdx.x;
  int swz = (bid & 7) * 128 + (bid >> 3);  // bijective XCD-chunk transform
  int c = swz >> 3;
  int t = swz & 7;
  int i0 = (t >> 1) << 7;          // 4 i-tiles of 128
  int j0 = (t & 1) << 8;           // 2 j-tiles of 256
  const u16* Lg = Lt + (size_t)c * NN_ + (size_t)i0 * 512;
  const u16* Rg = Rt + (size_t)c * NN_ + (size_t)j0 * 512;

  int l = tid & 63, w = tid >> 6;
  int wr = w >> 2, wc = w & 3;     // 2 i-bands x 4 j-bands of 64
  int lr = l & 15, lk = l >> 4;

  f32x4_t acc[4][4];
#pragma unroll
  for (int m = 0; m < 4; ++m)
#pragma unroll
    for (int n = 0; n < 4; ++n) acc[m][n] = (f32x4_t){0.f, 0.f, 0.f, 0.f};

  for (int kt = 0; kt < 512; kt += 64) {
#pragma unroll
    for (int q = 0; q < 2; ++q) {
      int s = q * 512 + tid;
      int row = s >> 3;
      int k8 = (s & 7) ^ (row & 7);
      gld_lds16(La + s * 8, Lg + (size_t)row * 512 + kt + k8 * 8);
    }
#pragma unroll
    for (int q = 0; q < 4; ++q) {
      int s = q * 512 + tid;
      int row = s >> 3;
      int k8 = (s & 7) ^ (row & 7);
      gld_lds16(Rb + s * 8, Rg + (size_t)row * 512 + kt + k8 * 8);
    }
    __syncthreads();

    __builtin_amdgcn_s_setprio(1);
#pragma unroll
    for (int ks = 0; ks < 2; ++ks) {
      int kb = ks * 4 + lk;
      bf16x8_t af[4], bf[4];
#pragma unroll
      for (int m = 0; m < 4; ++m) {
        int row = wr * 64 + m * 16 + lr;
        af[m] = *(const bf16x8_t*)(La + row * 64 + ((kb ^ (row & 7)) * 8));
      }
#pragma unroll
      for (int n = 0; n < 4; ++n) {
        int row = wc * 64 + n * 16 + lr;
        bf[n] = *(const bf16x8_t*)(Rb + row * 64 + ((kb ^ (row & 7)) * 8));
      }
#pragma unroll
      for (int m = 0; m < 4; ++m)
#pragma unroll
        for (int n = 0; n < 4; ++n)
          acc[m][n] = __builtin_amdgcn_mfma_f32_16x16x32_bf16(af[m], bf[n], acc[m][n], 0, 0, 0);
    }
    __builtin_amdgcn_s_setprio(0);
    __syncthreads();
  }

#pragma unroll
  for (int h = 0; h < 2; ++h) {
    if ((wc >> 1) == h) {
#pragma unroll
      for (int m = 0; m < 4; ++m) {
        int row0 = wr * 64 + m * 16 + lk * 4;
#pragma unroll
        for (int n = 0; n < 4; ++n) {
          int col = ((wc & 1) * 64 + n * 16 + lr) ^ (lk << 4);
#pragma unroll
          for (int r = 0; r < 4; ++r)
            ob[(row0 + r) * 128 + col] = f2bf(acc[m][n][r]);
        }
      }
    }
    __syncthreads();
#pragma unroll
    for (int it = 0; it < 4; ++it) {
      int s = it * 512 + tid;
      int row = s >> 4, c8 = s & 15;
      int g = (row >> 2) & 3;
      const u16* src = ob + row * 128 + ((c8 * 8) ^ (g << 4));
      *(uint4*)(Ot + (size_t)c * NN_ + (size_t)(i0 + row) * 512 + j0 + h * 128 + c8 * 8) =
          *(const uint4*)src;
    }
    __syncthreads();
  }
}

// ---------------------------------------------------------------------------
// K4 (MFMA) v2: gate GEMM (phase A: Gx+wgate staged, gate -> bf16 regs) then
// center LN + out-proj (phase B reuses the same 64KB) + gated epilogue.
// ---------------------------------------------------------------------------
__global__ __launch_bounds__(512, 4) void k4_mfma(const u16* __restrict__ Ot,
                                                  const u16* __restrict__ Gx,
                                                  const u16* __restrict__ wtbase,
                                                  const u16* __restrict__ Wt6,
                                                  const float* __restrict__ bgate,
                                                  const float* __restrict__ gc,
                                                  const float* __restrict__ bc,
                                                  const float* __restrict__ bout,
                                                  float* __restrict__ out) {
  __shared__ __align__(16) unsigned char smem[70656];
  u16* xg = (u16*)smem;                       // phase A: [128 p][128 c] (swz rows)
  u16* wg = (u16*)(smem + 32768);             // phase A: wgate [128 o][128 c] swz
  u16* ot = (u16*)smem;                       // phase B: Ot tile (overwrites xg)
  u16* ws = (u16*)(smem + 32768);             // phase B: Wt6 (overwrites wg)
  float* ps = (float*)(smem + 65536);         // [4][128]
  float* pss = (float*)(smem + 67584);        // [4][128]
  float2* munr = (float2*)(smem + 69632);     // [128]

  int tid = threadIdx.x;
  int l = tid & 63, w = tid >> 6;
  int wr = w >> 1, wc = w & 1;
  int lr = l & 15, lk = l >> 4;
  size_t p0 = (size_t)blockIdx.x * 128;
  int i_row = (int)(p0 >> 9);
  int j0 = (int)(p0 & 511);

  // ---- phase A: stage xg (raw swizzled rows) + wgate ----
#pragma unroll
  for (int q = 0; q < 4; ++q) {
    int s = q * 512 + tid;
    int row = s >> 4, c8 = s & 15;
    gld_lds16(xg + s * 8, Gx + (p0 + row) * 128 + c8 * 8);
  }
  {
    const u16* wsrc = wtbase + 4 * 16384;  // wgate [o][k]
#pragma unroll
    for (int q = 0; q < 4; ++q) {
      int s = q * 512 + tid;
      int row = s >> 4, j = (s & 15) ^ (row & 7);
      gld_lds16(wg + s * 8, wsrc + row * 128 + j * 8);
    }
  }
  __syncthreads();

  // gate GEMM: gate[p][o] = xg[p][:] . wg[o][:]
  f32x4_t gacc[2][4];
#pragma unroll
  for (int m = 0; m < 2; ++m)
#pragma unroll
    for (int n = 0; n < 4; ++n) gacc[m][n] = (f32x4_t){0.f, 0.f, 0.f, 0.f};

  __builtin_amdgcn_s_setprio(1);
#pragma unroll
  for (int kt = 0; kt < 4; ++kt) {
    int kb = kt * 4 + lk;
    bf16x8_t af[2], bf[4];
#pragma unroll
    for (int m = 0; m < 2; ++m) {
      int row = wr * 32 + m * 16 + lr;
      af[m] = *(const bf16x8_t*)(xg + row * 128 + ((kb ^ (row & 7)) * 8));
    }
#pragma unroll
    for (int n = 0; n < 4; ++n) {
      int o = wc * 64 + n * 16 + lr;
      bf[n] = *(const bf16x8_t*)(wg + o * 128 + ((kb ^ (o & 7)) * 8));
    }
#pragma unroll
    for (int m = 0; m < 2; ++m)
#pragma unroll
      for (int n = 0; n < 4; ++n)
        gacc[m][n] = __builtin_amdgcn_mfma_f32_16x16x32_bf16(af[m], bf[n], gacc[m][n], 0, 0, 0);
  }
  __builtin_amdgcn_s_setprio(0);

  // compress gate+bias to bf16 (same rounding as the old Gs path); 16 VGPR
  ushort4 gb[2][4];
#pragma unroll
  for (int n = 0; n < 4; ++n) {
    float bg = bgate[wc * 64 + n * 16 + lr];
#pragma unroll
    for (int m = 0; m < 2; ++m) {
      gb[m][n].x = f2bf(gacc[m][n][0] + bg);
      gb[m][n].y = f2bf(gacc[m][n][1] + bg);
      gb[m][n].z = f2bf(gacc[m][n][2] + bg);
      gb[m][n].w = f2bf(gacc[m][n][3] + bg);
    }
  }
  __syncthreads();  // xg/wg reads done; safe to overwrite

  // ---- phase B: stage Ot tile + Wt6 ----
#pragma unroll
  for (int q = 0; q < 4; ++q) {
    int s = q * 512 + tid;
    int cc = s >> 4, j = s & 15;
    gld_lds16(ot + s * 8, Ot + (size_t)cc * NN_ + (size_t)i_row * 512 + j0 + j * 8);
  }
#pragma unroll
  for (int q = 0; q < 4; ++q) {
    int s = q * 512 + tid;
    int o = s >> 4, j = (s & 15) ^ (o & 7);
    gld_lds16(ws + s * 8, Wt6 + o * 128 + j * 8);
  }
  __syncthreads();

  int g = tid >> 7, pos = tid & 127;
  float vals[32];
  float s1 = 0.0f, s2 = 0.0f;
#pragma unroll
  for (int m = 0; m < 32; ++m) {
    float v = bf2f(ot[(g * 32 + m) * 128 + pos]);
    vals[m] = v;
    s1 += v;
    s2 += v * v;
  }
  ps[g * 128 + pos] = s1;
  pss[g * 128 + pos] = s2;
  __syncthreads();
  if (tid < 128) {
    float a = ps[tid] + ps[128 + tid] + ps[256 + tid] + ps[384 + tid];
    float b = pss[tid] + pss[128 + tid] + pss[256 + tid] + pss[384 + tid];
    float mu = a * (1.0f / 128.0f);
    float rstd = rsqrtf(b * (1.0f / 128.0f) - mu * mu + 1e-5f);
    munr[tid] = make_float2(mu, rstd);
  }
  __syncthreads();
  float2 mr = munr[pos];

  u16* xn = ot;
#pragma unroll
  for (int mm = 0; mm < 4; ++mm) {
    int c8 = g * 4 + mm;
    ushort4 va, vb;
    int cb = c8 * 8;
    va.x = f2bf((vals[mm * 8 + 0] - mr.x) * mr.y * gc[cb + 0] + bc[cb + 0]);
    va.y = f2bf((vals[mm * 8 + 1] - mr.x) * mr.y * gc[cb + 1] + bc[cb + 1]);
    va.z = f2bf((vals[mm * 8 + 2] - mr.x) * mr.y * gc[cb + 2] + bc[cb + 2]);
    va.w = f2bf((vals[mm * 8 + 3] - mr.x) * mr.y * gc[cb + 3] + bc[cb + 3]);
    vb.x = f2bf((vals[mm * 8 + 4] - mr.x) * mr.y * gc[cb + 4] + bc[cb + 4]);
    vb.y = f2bf((vals[mm * 8 + 5] - mr.x) * mr.y * gc[cb + 5] + bc[cb + 5]);
    vb.z = f2bf((vals[mm * 8 + 6] - mr.x) * mr.y * gc[cb + 6] + bc[cb + 6]);
    vb.w = f2bf((vals[mm * 8 + 7] - mr.x) * mr.y * gc[cb + 7] + bc[cb + 7]);
    int slot = (c8 ^ (pos & 7)) * 8;
    *(ushort4*)(xn + pos * 128 + slot) = va;
    *(ushort4*)(xn + pos * 128 + slot + 4) = vb;
  }
  __syncthreads();

  f32x4_t acc[2][4];
#pragma unroll
  for (int m = 0; m < 2; ++m)
#pragma unroll
    for (int n = 0; n < 4; ++n) acc[m][n] = (f32x4_t){0.f, 0.f, 0.f, 0.f};

  __builtin_amdgcn_s_setprio(1);
#pragma unroll
  for (int kt = 0; kt < 4; ++kt) {
    int kb = kt * 4 + lk;
    bf16x8_t af[2], bf[4];
#pragma unroll
    for (int m = 0; m < 2; ++m) {
      int row = wr * 32 + m * 16 + lr;
      af[m] = *(const bf16x8_t*)(xn + row * 128 + ((kb ^ (row & 7)) * 8));
    }
#pragma unroll
    for (int n = 0; n < 4; ++n) {
      int o = wc * 64 + n * 16 + lr;
      bf[n] = *(const bf16x8_t*)(ws + o * 128 + ((kb ^ (o & 7)) * 8));
    }
#pragma unroll
    for (int m = 0; m < 2; ++m)
#pragma unroll
      for (int n = 0; n < 4; ++n)
        acc[m][n] = __builtin_amdgcn_mfma_f32_16x16x32_bf16(af[m], bf[n], acc[m][n], 0, 0, 0);
  }
  __builtin_amdgcn_s_setprio(0);

  // epilogue: (acc + bout) * sigm(gate from registers) -> os -> float4 stores
  float* os = (float*)(smem + 32768);  // [64][128] f32 per half
#pragma unroll
  for (int h = 0; h < 2; ++h) {
    __syncthreads();
    if ((wr >> 1) == h) {
#pragma unroll
      for (int n = 0; n < 4; ++n) {
        int o = wc * 64 + n * 16 + lr;
        float bo = bout[o];
#pragma unroll
        for (int m = 0; m < 2; ++m) {
          int p = (wr & 1) * 32 + m * 16 + lk * 4;
          float gv[4] = {sigm(bf2f(gb[m][n].x)), sigm(bf2f(gb[m][n].y)),
                         sigm(bf2f(gb[m][n].z)), sigm(bf2f(gb[m][n].w))};
#pragma unroll
          for (int r = 0; r < 4; ++r) {
            int row = p + r;
            os[row * 128 + (o ^ (((row >> 2) & 7) << 4))] = (acc[m][n][r] + bo) * gv[r];
          }
        }
      }
    }
    __syncthreads();
#pragma unroll
    for (int it = 0; it < 4; ++it) {
      int s = it * 512 + tid;
      int row = s >> 5, sl = s & 31;
      float4 v = *(const float4*)(os + row * 128 + ((sl * 4) ^ (((row >> 2) & 7) << 4)));
      *(float4*)(out + (p0 + h * 64 + row) * 128 + sl * 4) = v;
    }
  }
}

// ---------------------------------------------------------------------------
extern "C" void kernel_launch(void* const* d_in, const int* in_sizes, int n_in,
                              void* d_out, int out_size, void* d_ws, size_t ws_size,
                              hipStream_t stream) {
  const float* act    = (const float*)d_in[0];
  const float* mask   = (const float*)d_in[1];
  const float* ln_in_g = (const float*)d_in[2];
  const float* ln_in_b = (const float*)d_in[3];
  const float* wl     = (const float*)d_in[4];
  const float* bl     = (const float*)d_in[5];
  const float* wr     = (const float*)d_in[6];
  const float* br     = (const float*)d_in[7];
  const float* wgl    = (const float*)d_in[8];
  const float* bgl    = (const float*)d_in[9];
  const float* wgr    = (const float*)d_in[10];
  const float* bgr    = (const float*)d_in[11];
  const float* wgate  = (const float*)d_in[12];
  const float* bgate  = (const float*)d_in[13];
  const float* ln_c_g = (const float*)d_in[14];
  const float* ln_c_b = (const float*)d_in[15];
  const float* wout   = (const float*)d_in[16];
  const float* bout   = (const float*)d_in[17];
  float* out = (float*)d_out;

  char* ws = (char*)d_ws;
  const size_t SEG = 1ull << 26;  // 64 MiB per bf16 [128][512][512] buffer
  u16* Lt  = (u16*)(ws);
  u16* Rt  = (u16*)(ws + 1 * SEG);
  u16* Gx  = (u16*)(ws + 2 * SEG);  // xln export [p][c] (swizzled rows)
  u16* Ot  = (u16*)(ws + 3 * SEG);
  u16* Wt6 = Lt;   // alias: Lt dead after k3; k0b writes, k4 reads

  // Wt scratch for the 5 projection weights in the tail of d_out.
  u16* wtbase = (u16*)((char*)d_out + (size_t)out_size * 4 - 5 * 32768);

  k0_wt<<<dim3(40), dim3(256), 0, stream>>>(wl, wgl, wr, wgr, wgate, wtbase);
  k2_fused<<<dim3(1024), dim3(512), 0, stream>>>(act, mask, wtbase, ln_in_g, ln_in_b,
                                                 bl, bgl, br, bgr, Lt, Rt, Gx);
  k3_einsum_mfma<<<dim3(1024), dim3(512), 0, stream>>>(Lt, Rt, Ot);
  k0b<<<dim3(8), dim3(256), 0, stream>>>(wout, Wt6);
  k4_mfma<<<dim3(2048), dim3(512), 0, stream>>>(Ot, Gx, wtbase, Wt6, bgate,
                                                ln_c_g, ln_c_b, bout, out);
}

// Round 22
// 239.605 us; speedup vs baseline: 1.2184x; 1.2184x over previous
//
#include <hip/hip_runtime.h>

#define NPOS 512
#define NN_ (512 * 512)

typedef unsigned short u16;
typedef __attribute__((ext_vector_type(8))) short bf16x8_t;  // 8 bf16 in 4 VGPRs
typedef __attribute__((ext_vector_type(4))) float f32x4_t;   // MFMA acc

__device__ __forceinline__ float bf2f(u16 u) {
  union { unsigned int i; float f; } v;
  v.i = ((unsigned int)u) << 16;
  return v.f;
}
// Native HW bf16 convert (RNE).
__device__ __forceinline__ u16 f2bf(float f) {
  __bf16 h = (__bf16)f;
  return __builtin_bit_cast(unsigned short, h);
}
__device__ __forceinline__ float sigm(float x) { return 1.0f / (1.0f + __expf(-x)); }

// async global->LDS, 16B per lane (dest must be wave-linear: base + lane*16).
__device__ __forceinline__ void gld_lds16(u16* lds, const u16* g) {
  __builtin_amdgcn_global_load_lds(
      (const __attribute__((address_space(1))) unsigned int*)g,
      (__attribute__((address_space(3))) unsigned int*)lds, 16, 0, 0);
}

// ---------------------------------------------------------------------------
// K0: pre-transpose 5 projection weights to bf16 Wt[o][k] (k contiguous).
// ---------------------------------------------------------------------------
__global__ __launch_bounds__(256) void k0_wt(const float* __restrict__ wl,
                                             const float* __restrict__ wgl,
                                             const float* __restrict__ wr,
                                             const float* __restrict__ wgr,
                                             const float* __restrict__ wgate,
                                             u16* __restrict__ wtbase) {
  int b = blockIdx.x;
  int wi = b >> 3;
  int o0 = (b & 7) * 16;
  const float* W = wi == 0 ? wl : wi == 1 ? wgl : wi == 2 ? wr : wi == 3 ? wgr : wgate;
  u16* dst = wtbase + wi * 16384;
  int t = threadIdx.x;
  int o = o0 + (t >> 4);
  int k0 = (t & 15) * 8;
  float v[8];
#pragma unroll
  for (int i = 0; i < 8; ++i) v[i] = W[(k0 + i) * 128 + o];
  ushort4 a, b4;
  a.x = f2bf(v[0]); a.y = f2bf(v[1]); a.z = f2bf(v[2]); a.w = f2bf(v[3]);
  b4.x = f2bf(v[4]); b4.y = f2bf(v[5]); b4.z = f2bf(v[6]); b4.w = f2bf(v[7]);
  *(ushort4*)(dst + o * 128 + k0) = a;
  *(ushort4*)(dst + o * 128 + k0 + 4) = b4;
}

// ---------------------------------------------------------------------------
// K0b: transpose wout -> bf16 Wt6[o][k], into dead Lt region (after k3).
// ---------------------------------------------------------------------------
__global__ __launch_bounds__(256) void k0b(const float* __restrict__ wout,
                                           u16* __restrict__ Wt6) {
  int o = blockIdx.x * 16 + (threadIdx.x >> 4);
  int k0 = (threadIdx.x & 15) * 8;
  float v[8];
#pragma unroll
  for (int i = 0; i < 8; ++i) v[i] = wout[(k0 + i) * 128 + o];
  ushort4 a, b4;
  a.x = f2bf(v[0]); a.y = f2bf(v[1]); a.z = f2bf(v[2]); a.w = f2bf(v[3]);
  b4.x = f2bf(v[4]); b4.y = f2bf(v[5]); b4.z = f2bf(v[6]); b4.w = f2bf(v[7]);
  *(ushort4*)(Wt6 + o * 128 + k0) = a;
  *(ushort4*)(Wt6 + o * 128 + k0 + 4) = b4;
}

// ---------------------------------------------------------------------------
// K2_fused v10 (R20 best): input LN + 4 projection GEMMs, TWO 128-pos tiles
// per block sharing each staged weight pair. Tile0 A-frags in registers,
// tile1 A from xn LDS. Gx export fused into LN. LDS 80KB, grid 1024.
// NOTE (R21 lesson): do NOT hoist mask/epilogue values across sections —
// long live-ranges across the barrier-rich body spill to scratch at the
// pinned 128-VGPR budget (R21: +306MB scratch traffic, k2 121->174us).
// ---------------------------------------------------------------------------
__global__ __launch_bounds__(512, 4) void k2_fused(
    const float* __restrict__ act, const float* __restrict__ mask,
    const u16* __restrict__ wtbase,
    const float* __restrict__ ln_g, const float* __restrict__ ln_b,
    const float* __restrict__ bl, const float* __restrict__ bgl,
    const float* __restrict__ br, const float* __restrict__ bgr,
    u16* __restrict__ Lt, u16* __restrict__ Rt, u16* __restrict__ Gx) {
  __shared__ __align__(16) unsigned char smem[81920];
  u16* xn  = (u16*)smem;                     // [128 p][128 c] swizzled (tile1 resident)
  u16* wh0 = (u16*)(smem + 32768);           // [64 o][128 k] proj half
  u16* wh1 = (u16*)(smem + 49152);           // [64 o][128 k] gate half
  u16* ob  = (u16*)(smem + 65536);           // [64 o][128 p] epilogue buffer

  int tid = threadIdx.x;
  int l = tid & 63, w = tid >> 6;
  int wr_ = w >> 1, wc = w & 1;              // 32-pos band x 32-out band
  int lr = l & 15, lk = l >> 4;
  size_t p0 = (size_t)blockIdx.x * 256;      // tile0 base
  size_t p1 = p0 + 128;                      // tile1 base

#define STAGE(i_, buf_)                                                     \
  {                                                                         \
    const u16* src = wtbase + ((i_) >> 1) * 16384 + ((i_) & 1) * 8192;      \
    _Pragma("unroll") for (int q = 0; q < 2; ++q) {                         \
      int s = q * 512 + tid;                                                \
      int row = s >> 4, j = (s & 15) ^ (row & 7);                           \
      gld_lds16((buf_) + s * 8, src + row * 128 + j * 8);                   \
    }                                                                       \
  }
#define ZERO(ACC)                                                           \
  { ACC[0][0] = (f32x4_t){0.f, 0.f, 0.f, 0.f};                              \
    ACC[0][1] = (f32x4_t){0.f, 0.f, 0.f, 0.f};                              \
    ACC[1][0] = (f32x4_t){0.f, 0.f, 0.f, 0.f};                              \
    ACC[1][1] = (f32x4_t){0.f, 0.f, 0.f, 0.f}; }
// tile0 MF step: A from named registers
#define MFK0(buf_, ACC, KT, AF0, AF1)                                       \
  {                                                                         \
    int kb = (KT) * 4 + lk;                                                 \
    int o0_ = wc * 32 + lr, o1_ = wc * 32 + 16 + lr;                        \
    bf16x8_t bfr0 = *(const bf16x8_t*)((buf_) + o0_ * 128 + ((kb ^ (o0_ & 7)) * 8)); \
    bf16x8_t bfr1 = *(const bf16x8_t*)((buf_) + o1_ * 128 + ((kb ^ (o1_ & 7)) * 8)); \
    ACC[0][0] = __builtin_amdgcn_mfma_f32_16x16x32_bf16(AF0, bfr0, ACC[0][0], 0, 0, 0); \
    ACC[0][1] = __builtin_amdgcn_mfma_f32_16x16x32_bf16(AF0, bfr1, ACC[0][1], 0, 0, 0); \
    ACC[1][0] = __builtin_amdgcn_mfma_f32_16x16x32_bf16(AF1, bfr0, ACC[1][0], 0, 0, 0); \
    ACC[1][1] = __builtin_amdgcn_mfma_f32_16x16x32_bf16(AF1, bfr1, ACC[1][1], 0, 0, 0); \
  }
#define MF0(buf_, ACC)                                                      \
  MFK0(buf_, ACC, 0, af00, af10)                                            \
  MFK0(buf_, ACC, 1, af01, af11)                                            \
  MFK0(buf_, ACC, 2, af02, af12)                                            \
  MFK0(buf_, ACC, 3, af03, af13)
// tile1 MF step: A from xn LDS
#define MFK1(buf_, ACC, KT)                                                 \
  {                                                                         \
    int kb = (KT) * 4 + lk;                                                 \
    int r0_ = wr_ * 32 + lr, r1_ = wr_ * 32 + 16 + lr;                      \
    bf16x8_t a0_ = *(const bf16x8_t*)(xn + r0_ * 128 + ((kb ^ (r0_ & 7)) * 8)); \
    bf16x8_t a1_ = *(const bf16x8_t*)(xn + r1_ * 128 + ((kb ^ (r1_ & 7)) * 8)); \
    int o0_ = wc * 32 + lr, o1_ = wc * 32 + 16 + lr;                        \
    bf16x8_t bfr0 = *(const bf16x8_t*)((buf_) + o0_ * 128 + ((kb ^ (o0_ & 7)) * 8)); \
    bf16x8_t bfr1 = *(const bf16x8_t*)((buf_) + o1_ * 128 + ((kb ^ (o1_ & 7)) * 8)); \
    ACC[0][0] = __builtin_amdgcn_mfma_f32_16x16x32_bf16(a0_, bfr0, ACC[0][0], 0, 0, 0); \
    ACC[0][1] = __builtin_amdgcn_mfma_f32_16x16x32_bf16(a0_, bfr1, ACC[0][1], 0, 0, 0); \
    ACC[1][0] = __builtin_amdgcn_mfma_f32_16x16x32_bf16(a1_, bfr0, ACC[1][0], 0, 0, 0); \
    ACC[1][1] = __builtin_amdgcn_mfma_f32_16x16x32_bf16(a1_, bfr1, ACC[1][1], 0, 0, 0); \
  }
#define MF1(buf_, ACC)                                                      \
  MFK1(buf_, ACC, 0) MFK1(buf_, ACC, 1) MFK1(buf_, ACC, 2) MFK1(buf_, ACC, 3)
#define EPW(ACCP, ACCG, Bp_, Bg_, obase_, TB_)                              \
  {                                                                         \
    float bpv[2], bgv[2];                                                   \
    _Pragma("unroll") for (int n = 0; n < 2; ++n) {                         \
      int og = (obase_) + wc * 32 + n * 16 + lr;                            \
      bpv[n] = Bp_[og]; bgv[n] = Bg_[og];                                   \
    }                                                                       \
    _Pragma("unroll") for (int m = 0; m < 2; ++m) {                         \
      int p4 = wr_ * 32 + m * 16 + lk * 4;                                  \
      float4 mk = *(const float4*)(mask + (TB_) + p4);                      \
      int slot = p4 >> 3, off = p4 & 7;                                     \
      _Pragma("unroll") for (int n = 0; n < 2; ++n) {                       \
        int ol = wc * 32 + n * 16 + lr;                                     \
        ushort4 v;                                                          \
        v.x = f2bf(mk.x * (ACCP[m][n][0] + bpv[n]) * sigm(ACCG[m][n][0] + bgv[n])); \
        v.y = f2bf(mk.y * (ACCP[m][n][1] + bpv[n]) * sigm(ACCG[m][n][1] + bgv[n])); \
        v.z = f2bf(mk.z * (ACCP[m][n][2] + bpv[n]) * sigm(ACCG[m][n][2] + bgv[n])); \
        v.w = f2bf(mk.w * (ACCP[m][n][3] + bpv[n]) * sigm(ACCG[m][n][3] + bgv[n])); \
        *(ushort4*)(ob + ol * 128 + ((slot ^ (ol & 7)) << 3) + off) = v;    \
      }                                                                     \
    }                                                                       \
  }
#define EPS(Tdst_, obase_, TB_)                                             \
  {                                                                         \
    _Pragma("unroll") for (int it = 0; it < 2; ++it) {                      \
      int s = it * 512 + tid;                                               \
      int ol = s >> 4, c8 = s & 15;                                         \
      *(uint4*)(Tdst_ + (size_t)((obase_) + ol) * NN_ + (TB_) + c8 * 8) =   \
          *(const uint4*)(ob + ol * 128 + ((c8 ^ (ol & 7)) << 3));          \
    }                                                                       \
  }
// LN for one tile into xn; Gx export fused (coalesced 256B per 32-lane group)
#define LN_TILE(TB_)                                                        \
  _Pragma("unroll")                                                         \
  for (int r = 0; r < 8; ++r) {                                             \
    int f = r * 512 + tid;                                                  \
    int pos = f >> 5, c4 = f & 31;                                          \
    float4 v = *(const float4*)(act + ((TB_) + pos) * 128 + c4 * 4);        \
    float s1 = v.x + v.y + v.z + v.w;                                       \
    float s2 = v.x * v.x + v.y * v.y + v.z * v.z + v.w * v.w;               \
    _Pragma("unroll") for (int m = 1; m < 32; m <<= 1) {                    \
      s1 += __shfl_xor(s1, m);                                              \
      s2 += __shfl_xor(s2, m);                                              \
    }                                                                       \
    float mu = s1 * (1.0f / 128.0f);                                        \
    float rstd = rsqrtf(s2 * (1.0f / 128.0f) - mu * mu + 1e-5f);            \
    int cb = c4 * 4;                                                        \
    float4 gg = *(const float4*)(ln_g + cb);                                \
    float4 bb = *(const float4*)(ln_b + cb);                                \
    ushort4 o4;                                                             \
    o4.x = f2bf((v.x - mu) * rstd * gg.x + bb.x);                           \
    o4.y = f2bf((v.y - mu) * rstd * gg.y + bb.y);                           \
    o4.z = f2bf((v.z - mu) * rstd * gg.z + bb.z);                           \
    o4.w = f2bf((v.w - mu) * rstd * gg.w + bb.w);                           \
    int c8 = c4 >> 1, off = (c4 & 1) * 4;                                   \
    int so = pos * 128 + ((c8 ^ (pos & 7)) << 3) + off;                     \
    *(ushort4*)(xn + so) = o4;                                              \
    *(ushort4*)(Gx + (size_t)(TB_) * 128 + so) = o4;                        \
  }
// one weight half-pair section over both tiles
#define SECTION(Bp_, Bg_, obase_, Tdst_, DO_STAGE_, s0_, s1_)               \
  __builtin_amdgcn_s_setprio(1);                                            \
  ZERO(ap); MF0(wh0, ap);                                                   \
  ZERO(ag); MF0(wh1, ag);                                                   \
  __builtin_amdgcn_s_setprio(0);                                            \
  __syncthreads();                                                          \
  EPW(ap, ag, Bp_, Bg_, obase_, p0);                                        \
  __syncthreads();                                                          \
  EPS(Tdst_, obase_, p0);                                                   \
  __builtin_amdgcn_s_setprio(1);                                            \
  ZERO(ap); MF1(wh0, ap);                                                   \
  ZERO(ag); MF1(wh1, ag);                                                   \
  __builtin_amdgcn_s_setprio(0);                                            \
  __syncthreads();                                                          \
  if (DO_STAGE_) { STAGE(s0_, wh0); STAGE(s1_, wh1); }                      \
  EPW(ap, ag, Bp_, Bg_, obase_, p1);                                        \
  __syncthreads();                                                          \
  EPS(Tdst_, obase_, p1);

  // ---- prologue: issue wl.h0 + wgl.h0; LN both tiles; hoist tile0 ----
  STAGE(0, wh0);   // wl.h0
  STAGE(2, wh1);   // wgl.h0

  LN_TILE(p0);
  __syncthreads();                    // xn(tile0) visible

  bf16x8_t af00, af01, af02, af03, af10, af11, af12, af13;
  {
    int row0 = wr_ * 32 + lr;
    int row1 = wr_ * 32 + 16 + lr;
    const u16* x0 = xn + row0 * 128;
    const u16* x1 = xn + row1 * 128;
    af00 = *(const bf16x8_t*)(x0 + (((0 * 4 + lk) ^ (row0 & 7)) * 8));
    af01 = *(const bf16x8_t*)(x0 + (((1 * 4 + lk) ^ (row0 & 7)) * 8));
    af02 = *(const bf16x8_t*)(x0 + (((2 * 4 + lk) ^ (row0 & 7)) * 8));
    af03 = *(const bf16x8_t*)(x0 + (((3 * 4 + lk) ^ (row0 & 7)) * 8));
    af10 = *(const bf16x8_t*)(x1 + (((0 * 4 + lk) ^ (row1 & 7)) * 8));
    af11 = *(const bf16x8_t*)(x1 + (((1 * 4 + lk) ^ (row1 & 7)) * 8));
    af12 = *(const bf16x8_t*)(x1 + (((2 * 4 + lk) ^ (row1 & 7)) * 8));
    af13 = *(const bf16x8_t*)(x1 + (((3 * 4 + lk) ^ (row1 & 7)) * 8));
  }
  __syncthreads();                    // all hoist reads done -> xn reusable

  LN_TILE(p1);                        // tile1 LN into xn (stays resident)
  __syncthreads();                    // xn(tile1) visible; S0/S2 drained

  f32x4_t ap[2][2], ag[2][2];         // only TWO acc sets live at any time

  SECTION(bl, bgl, 0,  Lt, 1, 1, 3);  // L.h0 ; stage wl.h1, wgl.h1
  SECTION(bl, bgl, 64, Lt, 1, 4, 6);  // L.h1 ; stage wr.h0, wgr.h0
  SECTION(br, bgr, 0,  Rt, 1, 5, 7);  // R.h0 ; stage wr.h1, wgr.h1
  SECTION(br, bgr, 64, Rt, 0, 0, 0);  // R.h1 ; no further stages
#undef STAGE
#undef ZERO
#undef MFK0
#undef MF0
#undef MFK1
#undef MF1
#undef EPW
#undef EPS
#undef LN_TILE
#undef SECTION
}

// ---------------------------------------------------------------------------
// K3 (MFMA) v2: per-channel NT GEMM, 128x256 tile, 512 thr = 8 waves (2x4),
// each wave 64x64. LDS 48KB; XCD-chunked swizzle; setprio (T5).
// ---------------------------------------------------------------------------
__global__ __launch_bounds__(512, 4) void k3_einsum_mfma(const u16* __restrict__ Lt,
                                                         const u16* __restrict__ Rt,
                                                         u16* __restrict__ Ot) {
  __shared__ __align__(16) u16 smem[3 * 128 * 64];  // 48KB
  u16* La = smem;                 // [128][64]
  u16* Rb = smem + 128 * 64;      // [256][64]
  u16* ob = smem;                 // epilogue [128][128] overlay

  int tid = threadIdx.x;
  int bid = blockIdx.x;
  int swz = (bid & 7) * 128 + (bid >> 3);  // bijective XCD-chunk transform
  int c = swz >> 3;
  int t = swz & 7;
  int i0 = (t >> 1) << 7;          // 4 i-tiles of 128
  int j0 = (t & 1) << 8;           // 2 j-tiles of 256
  const u16* Lg = Lt + (size_t)c * NN_ + (size_t)i0 * 512;
  const u16* Rg = Rt + (size_t)c * NN_ + (size_t)j0 * 512;

  int l = tid & 63, w = tid >> 6;
  int wr = w >> 2, wc = w & 3;     // 2 i-bands x 4 j-bands of 64
  int lr = l & 15, lk = l >> 4;

  f32x4_t acc[4][4];
#pragma unroll
  for (int m = 0; m < 4; ++m)
#pragma unroll
    for (int n = 0; n < 4; ++n) acc[m][n] = (f32x4_t){0.f, 0.f, 0.f, 0.f};

  for (int kt = 0; kt < 512; kt += 64) {
#pragma unroll
    for (int q = 0; q < 2; ++q) {
      int s = q * 512 + tid;
      int row = s >> 3;
      int k8 = (s & 7) ^ (row & 7);
      gld_lds16(La + s * 8, Lg + (size_t)row * 512 + kt + k8 * 8);
    }
#pragma unroll
    for (int q = 0; q < 4; ++q) {
      int s = q * 512 + tid;
      int row = s >> 3;
      int k8 = (s & 7) ^ (row & 7);
      gld_lds16(Rb + s * 8, Rg + (size_t)row * 512 + kt + k8 * 8);
    }
    __syncthreads();

    __builtin_amdgcn_s_setprio(1);
#pragma unroll
    for (int ks = 0; ks < 2; ++ks) {
      int kb = ks * 4 + lk;
      bf16x8_t af[4], bf[4];
#pragma unroll
      for (int m = 0; m < 4; ++m) {
        int row = wr * 64 + m * 16 + lr;
        af[m] = *(const bf16x8_t*)(La + row * 64 + ((kb ^ (row & 7)) * 8));
      }
#pragma unroll
      for (int n = 0; n < 4; ++n) {
        int row = wc * 64 + n * 16 + lr;
        bf[n] = *(const bf16x8_t*)(Rb + row * 64 + ((kb ^ (row & 7)) * 8));
      }
#pragma unroll
      for (int m = 0; m < 4; ++m)
#pragma unroll
        for (int n = 0; n < 4; ++n)
          acc[m][n] = __builtin_amdgcn_mfma_f32_16x16x32_bf16(af[m], bf[n], acc[m][n], 0, 0, 0);
    }
    __builtin_amdgcn_s_setprio(0);
    __syncthreads();
  }

#pragma unroll
  for (int h = 0; h < 2; ++h) {
    if ((wc >> 1) == h) {
#pragma unroll
      for (int m = 0; m < 4; ++m) {
        int row0 = wr * 64 + m * 16 + lk * 4;
#pragma unroll
        for (int n = 0; n < 4; ++n) {
          int col = ((wc & 1) * 64 + n * 16 + lr) ^ (lk << 4);
#pragma unroll
          for (int r = 0; r < 4; ++r)
            ob[(row0 + r) * 128 + col] = f2bf(acc[m][n][r]);
        }
      }
    }
    __syncthreads();
#pragma unroll
    for (int it = 0; it < 4; ++it) {
      int s = it * 512 + tid;
      int row = s >> 4, c8 = s & 15;
      int g = (row >> 2) & 3;
      const u16* src = ob + row * 128 + ((c8 * 8) ^ (g << 4));
      *(uint4*)(Ot + (size_t)c * NN_ + (size_t)(i0 + row) * 512 + j0 + h * 128 + c8 * 8) =
          *(const uint4*)src;
    }
    __syncthreads();
  }
}

// ---------------------------------------------------------------------------
// K4 (MFMA) v2: gate GEMM (phase A: Gx+wgate staged, gate -> bf16 regs) then
// center LN + out-proj (phase B reuses the same 64KB) + gated epilogue.
// ---------------------------------------------------------------------------
__global__ __launch_bounds__(512, 4) void k4_mfma(const u16* __restrict__ Ot,
                                                  const u16* __restrict__ Gx,
                                                  const u16* __restrict__ wtbase,
                                                  const u16* __restrict__ Wt6,
                                                  const float* __restrict__ bgate,
                                                  const float* __restrict__ gc,
                                                  const float* __restrict__ bc,
                                                  const float* __restrict__ bout,
                                                  float* __restrict__ out) {
  __shared__ __align__(16) unsigned char smem[70656];
  u16* xg = (u16*)smem;                       // phase A: [128 p][128 c] (swz rows)
  u16* wg = (u16*)(smem + 32768);             // phase A: wgate [128 o][128 c] swz
  u16* ot = (u16*)smem;                       // phase B: Ot tile (overwrites xg)
  u16* ws = (u16*)(smem + 32768);             // phase B: Wt6 (overwrites wg)
  float* ps = (float*)(smem + 65536);         // [4][128]
  float* pss = (float*)(smem + 67584);        // [4][128]
  float2* munr = (float2*)(smem + 69632);     // [128]

  int tid = threadIdx.x;
  int l = tid & 63, w = tid >> 6;
  int wr = w >> 1, wc = w & 1;
  int lr = l & 15, lk = l >> 4;
  size_t p0 = (size_t)blockIdx.x * 128;
  int i_row = (int)(p0 >> 9);
  int j0 = (int)(p0 & 511);

  // ---- phase A: stage xg (raw swizzled rows) + wgate ----
#pragma unroll
  for (int q = 0; q < 4; ++q) {
    int s = q * 512 + tid;
    int row = s >> 4, c8 = s & 15;
    gld_lds16(xg + s * 8, Gx + (p0 + row) * 128 + c8 * 8);
  }
  {
    const u16* wsrc = wtbase + 4 * 16384;  // wgate [o][k]
#pragma unroll
    for (int q = 0; q < 4; ++q) {
      int s = q * 512 + tid;
      int row = s >> 4, j = (s & 15) ^ (row & 7);
      gld_lds16(wg + s * 8, wsrc + row * 128 + j * 8);
    }
  }
  __syncthreads();

  // gate GEMM: gate[p][o] = xg[p][:] . wg[o][:]
  f32x4_t gacc[2][4];
#pragma unroll
  for (int m = 0; m < 2; ++m)
#pragma unroll
    for (int n = 0; n < 4; ++n) gacc[m][n] = (f32x4_t){0.f, 0.f, 0.f, 0.f};

  __builtin_amdgcn_s_setprio(1);
#pragma unroll
  for (int kt = 0; kt < 4; ++kt) {
    int kb = kt * 4 + lk;
    bf16x8_t af[2], bf[4];
#pragma unroll
    for (int m = 0; m < 2; ++m) {
      int row = wr * 32 + m * 16 + lr;
      af[m] = *(const bf16x8_t*)(xg + row * 128 + ((kb ^ (row & 7)) * 8));
    }
#pragma unroll
    for (int n = 0; n < 4; ++n) {
      int o = wc * 64 + n * 16 + lr;
      bf[n] = *(const bf16x8_t*)(wg + o * 128 + ((kb ^ (o & 7)) * 8));
    }
#pragma unroll
    for (int m = 0; m < 2; ++m)
#pragma unroll
      for (int n = 0; n < 4; ++n)
        gacc[m][n] = __builtin_amdgcn_mfma_f32_16x16x32_bf16(af[m], bf[n], gacc[m][n], 0, 0, 0);
  }
  __builtin_amdgcn_s_setprio(0);

  // compress gate+bias to bf16 (same rounding as the old Gs path); 16 VGPR
  ushort4 gb[2][4];
#pragma unroll
  for (int n = 0; n < 4; ++n) {
    float bg = bgate[wc * 64 + n * 16 + lr];
#pragma unroll
    for (int m = 0; m < 2; ++m) {
      gb[m][n].x = f2bf(gacc[m][n][0] + bg);
      gb[m][n].y = f2bf(gacc[m][n][1] + bg);
      gb[m][n].z = f2bf(gacc[m][n][2] + bg);
      gb[m][n].w = f2bf(gacc[m][n][3] + bg);
    }
  }
  __syncthreads();  // xg/wg reads done; safe to overwrite

  // ---- phase B: stage Ot tile + Wt6 ----
#pragma unroll
  for (int q = 0; q < 4; ++q) {
    int s = q * 512 + tid;
    int cc = s >> 4, j = s & 15;
    gld_lds16(ot + s * 8, Ot + (size_t)cc * NN_ + (size_t)i_row * 512 + j0 + j * 8);
  }
#pragma unroll
  for (int q = 0; q < 4; ++q) {
    int s = q * 512 + tid;
    int o = s >> 4, j = (s & 15) ^ (o & 7);
    gld_lds16(ws + s * 8, Wt6 + o * 128 + j * 8);
  }
  __syncthreads();

  int g = tid >> 7, pos = tid & 127;
  float vals[32];
  float s1 = 0.0f, s2 = 0.0f;
#pragma unroll
  for (int m = 0; m < 32; ++m) {
    float v = bf2f(ot[(g * 32 + m) * 128 + pos]);
    vals[m] = v;
    s1 += v;
    s2 += v * v;
  }
  ps[g * 128 + pos] = s1;
  pss[g * 128 + pos] = s2;
  __syncthreads();
  if (tid < 128) {
    float a = ps[tid] + ps[128 + tid] + ps[256 + tid] + ps[384 + tid];
    float b = pss[tid] + pss[128 + tid] + pss[256 + tid] + pss[384 + tid];
    float mu = a * (1.0f / 128.0f);
    float rstd = rsqrtf(b * (1.0f / 128.0f) - mu * mu + 1e-5f);
    munr[tid] = make_float2(mu, rstd);
  }
  __syncthreads();
  float2 mr = munr[pos];

  u16* xn = ot;
#pragma unroll
  for (int mm = 0; mm < 4; ++mm) {
    int c8 = g * 4 + mm;
    ushort4 va, vb;
    int cb = c8 * 8;
    va.x = f2bf((vals[mm * 8 + 0] - mr.x) * mr.y * gc[cb + 0] + bc[cb + 0]);
    va.y = f2bf((vals[mm * 8 + 1] - mr.x) * mr.y * gc[cb + 1] + bc[cb + 1]);
    va.z = f2bf((vals[mm * 8 + 2] - mr.x) * mr.y * gc[cb + 2] + bc[cb + 2]);
    va.w = f2bf((vals[mm * 8 + 3] - mr.x) * mr.y * gc[cb + 3] + bc[cb + 3]);
    vb.x = f2bf((vals[mm * 8 + 4] - mr.x) * mr.y * gc[cb + 4] + bc[cb + 4]);
    vb.y = f2bf((vals[mm * 8 + 5] - mr.x) * mr.y * gc[cb + 5] + bc[cb + 5]);
    vb.z = f2bf((vals[mm * 8 + 6] - mr.x) * mr.y * gc[cb + 6] + bc[cb + 6]);
    vb.w = f2bf((vals[mm * 8 + 7] - mr.x) * mr.y * gc[cb + 7] + bc[cb + 7]);
    int slot = (c8 ^ (pos & 7)) * 8;
    *(ushort4*)(xn + pos * 128 + slot) = va;
    *(ushort4*)(xn + pos * 128 + slot + 4) = vb;
  }
  __syncthreads();

  f32x4_t acc[2][4];
#pragma unroll
  for (int m = 0; m < 2; ++m)
#pragma unroll
    for (int n = 0; n < 4; ++n) acc[m][n] = (f32x4_t){0.f, 0.f, 0.f, 0.f};

  __builtin_amdgcn_s_setprio(1);
#pragma unroll
  for (int kt = 0; kt < 4; ++kt) {
    int kb = kt * 4 + lk;
    bf16x8_t af[2], bf[4];
#pragma unroll
    for (int m = 0; m < 2; ++m) {
      int row = wr * 32 + m * 16 + lr;
      af[m] = *(const bf16x8_t*)(xn + row * 128 + ((kb ^ (row & 7)) * 8));
    }
#pragma unroll
    for (int n = 0; n < 4; ++n) {
      int o = wc * 64 + n * 16 + lr;
      bf[n] = *(const bf16x8_t*)(ws + o * 128 + ((kb ^ (o & 7)) * 8));
    }
#pragma unroll
    for (int m = 0; m < 2; ++m)
#pragma unroll
      for (int n = 0; n < 4; ++n)
        acc[m][n] = __builtin_amdgcn_mfma_f32_16x16x32_bf16(af[m], bf[n], acc[m][n], 0, 0, 0);
  }
  __builtin_amdgcn_s_setprio(0);

  // epilogue: (acc + bout) * sigm(gate from registers) -> os -> float4 stores
  float* os = (float*)(smem + 32768);  // [64][128] f32 per half
#pragma unroll
  for (int h = 0; h < 2; ++h) {
    __syncthreads();
    if ((wr >> 1) == h) {
#pragma unroll
      for (int n = 0; n < 4; ++n) {
        int o = wc * 64 + n * 16 + lr;
        float bo = bout[o];
#pragma unroll
        for (int m = 0; m < 2; ++m) {
          int p = (wr & 1) * 32 + m * 16 + lk * 4;
          float gv[4] = {sigm(bf2f(gb[m][n].x)), sigm(bf2f(gb[m][n].y)),
                         sigm(bf2f(gb[m][n].z)), sigm(bf2f(gb[m][n].w))};
#pragma unroll
          for (int r = 0; r < 4; ++r) {
            int row = p + r;
            os[row * 128 + (o ^ (((row >> 2) & 7) << 4))] = (acc[m][n][r] + bo) * gv[r];
          }
        }
      }
    }
    __syncthreads();
#pragma unroll
    for (int it = 0; it < 4; ++it) {
      int s = it * 512 + tid;
      int row = s >> 5, sl = s & 31;
      float4 v = *(const float4*)(os + row * 128 + ((sl * 4) ^ (((row >> 2) & 7) << 4)));
      *(float4*)(out + (p0 + h * 64 + row) * 128 + sl * 4) = v;
    }
  }
}

// ---------------------------------------------------------------------------
extern "C" void kernel_launch(void* const* d_in, const int* in_sizes, int n_in,
                              void* d_out, int out_size, void* d_ws, size_t ws_size,
                              hipStream_t stream) {
  const float* act    = (const float*)d_in[0];
  const float* mask   = (const float*)d_in[1];
  const float* ln_in_g = (const float*)d_in[2];
  const float* ln_in_b = (const float*)d_in[3];
  const float* wl     = (const float*)d_in[4];
  const float* bl     = (const float*)d_in[5];
  const float* wr     = (const float*)d_in[6];
  const float* br     = (const float*)d_in[7];
  const float* wgl    = (const float*)d_in[8];
  const float* bgl    = (const float*)d_in[9];
  const float* wgr    = (const float*)d_in[10];
  const float* bgr    = (const float*)d_in[11];
  const float* wgate  = (const float*)d_in[12];
  const float* bgate  = (const float*)d_in[13];
  const float* ln_c_g = (const float*)d_in[14];
  const float* ln_c_b = (const float*)d_in[15];
  const float* wout   = (const float*)d_in[16];
  const float* bout   = (const float*)d_in[17];
  float* out = (float*)d_out;

  char* ws = (char*)d_ws;
  const size_t SEG = 1ull << 26;  // 64 MiB per bf16 [128][512][512] buffer
  u16* Lt  = (u16*)(ws);
  u16* Rt  = (u16*)(ws + 1 * SEG);
  u16* Gx  = (u16*)(ws + 2 * SEG);  // xln export [p][c] (swizzled rows)
  u16* Ot  = (u16*)(ws + 3 * SEG);
  u16* Wt6 = Lt;   // alias: Lt dead after k3; k0b writes, k4 reads

  // Wt scratch for the 5 projection weights in the tail of d_out.
  u16* wtbase = (u16*)((char*)d_out + (size_t)out_size * 4 - 5 * 32768);

  k0_wt<<<dim3(40), dim3(256), 0, stream>>>(wl, wgl, wr, wgr, wgate, wtbase);
  k2_fused<<<dim3(1024), dim3(512), 0, stream>>>(act, mask, wtbase, ln_in_g, ln_in_b,
                                                 bl, bgl, br, bgr, Lt, Rt, Gx);
  k3_einsum_mfma<<<dim3(1024), dim3(512), 0, stream>>>(Lt, Rt, Ot);
  k0b<<<dim3(8), dim3(256), 0, stream>>>(wout, Wt6);
  k4_mfma<<<dim3(2048), dim3(512), 0, stream>>>(Ot, Gx, wtbase, Wt6, bgate,
                                                ln_c_g, ln_c_b, bout, out);
}